// Round 4
// baseline (9613.531 us; speedup 1.0000x reference)
//
#include <hip/hip_runtime.h>
#include <hip/hip_bf16.h>
#include <math.h>

typedef __hip_bfloat16 bf16;

#define D_MODEL 1024
#define NUM_HEADS 16
#define DK 64
#define SEQ 2048
#define BATCH 2

__device__ inline float2 bf2u_to_f2(unsigned u) {
    __hip_bfloat162 h = *reinterpret_cast<__hip_bfloat162*>(&u);
    return __bfloat1622float2(h);
}

// ---------------------------------------------------------------------------
// Kernel 1: QKV projection + RoPE. Inputs FP32. One block per (b,s) row;
// x-row staged in LDS; each thread computes 4 output columns per weight
// matrix with float4 weight loads. Q,K,V written bf16 to workspace in
// (B,H,S,dk) layout (24 MB total).
// ---------------------------------------------------------------------------
__global__ __launch_bounds__(256) void qkv_rope_kernel(
    const float* __restrict__ x, const int* __restrict__ pos,
    const float* __restrict__ Wq, const float* __restrict__ Wk,
    const float* __restrict__ Wv,
    bf16* __restrict__ Q, bf16* __restrict__ K, bf16* __restrict__ V)
{
    __shared__ float xs[D_MODEL];
    __shared__ float row[D_MODEL];
    const int bs = blockIdx.x;
    const int b = bs / SEQ;
    const int s = bs - b * SEQ;
    const int t = threadIdx.x;

    const float* xrow = x + (size_t)bs * D_MODEL;
    for (int i = t; i < D_MODEL; i += 256) xs[i] = xrow[i];
    __syncthreads();

    // token_positions: int32 (pos[1]==1) or int64 little-endian (pos[1]==0).
    const int p = (pos[1] == 0) ? pos[2 * s] : pos[s];

    for (int which = 0; which < 3; ++which) {
        const float* W = (which == 0) ? Wq : (which == 1) ? Wk : Wv;
        #pragma unroll
        for (int j = 0; j < 4; ++j) {
            const int n = t + 256 * j;
            const float4* w4 = reinterpret_cast<const float4*>(W + (size_t)n * D_MODEL);
            float acc = 0.f;
            #pragma unroll 8
            for (int k = 0; k < D_MODEL / 4; ++k) {
                float4 wf = w4[k];
                acc = fmaf(xs[4 * k],     wf.x, acc);
                acc = fmaf(xs[4 * k + 1], wf.y, acc);
                acc = fmaf(xs[4 * k + 2], wf.z, acc);
                acc = fmaf(xs[4 * k + 3], wf.w, acc);
            }
            row[n] = acc;
        }
        __syncthreads();
        if (which < 2) {
            bf16* dst = (which == 0) ? Q : K;
            #pragma unroll
            for (int j = 0; j < 2; ++j) {
                const int pr = t + 256 * j;   // pair index 0..511 (32 pairs/head)
                const int h = pr >> 5;
                const int i = pr & 31;
                const float freq = __expf((float)(2 * i) * (-9.2103403719761836f / 64.f));
                const float ang = (float)p * freq;
                const float sn = sinf(ang), cs = cosf(ang);
                const float x0 = row[2 * pr], x1 = row[2 * pr + 1];
                const size_t base =
                    (((size_t)(b * NUM_HEADS + h)) * SEQ + s) * DK + 2 * i;
                __hip_bfloat162 val;
                val.x = __float2bfloat16(x0 * cs - x1 * sn);
                val.y = __float2bfloat16(x0 * sn + x1 * cs);
                *reinterpret_cast<__hip_bfloat162*>(dst + base) = val;
            }
        } else {
            #pragma unroll
            for (int j = 0; j < 4; ++j) {
                const int n = t + 256 * j;
                const int h = n >> 6, d = n & 63;
                V[(((size_t)(b * NUM_HEADS + h)) * SEQ + s) * DK + d] =
                    __float2bfloat16(row[n]);
            }
        }
        __syncthreads();
    }
}

// ---------------------------------------------------------------------------
// Kernel 2: causal attention, one block per (b,h,q) row. Scores row in LDS,
// two-pass softmax; PV phase with thread=(kgroup,dim) for coalesced V reads.
// Output written FP32 into d_out (B,S,H*dk), consumed by oproj.
// ---------------------------------------------------------------------------
__global__ __launch_bounds__(256) void attn_kernel(
    const bf16* __restrict__ Q, const bf16* __restrict__ K,
    const bf16* __restrict__ V, float* __restrict__ O)
{
    const int q = blockIdx.x;
    const int bh = blockIdx.y;
    const int t = threadIdx.x;
    __shared__ float sc[SEQ];
    __shared__ float qs[DK];
    __shared__ float rbuf[256];
    __shared__ float obuf[4][DK];

    const bf16* Qr = Q + ((size_t)bh * SEQ + q) * DK;
    if (t < DK) qs[t] = __bfloat162float(Qr[t]);
    __syncthreads();

    const int L = q + 1;
    const bf16* Kbase = K + (size_t)bh * SEQ * DK;

    float lmax = -3.0e38f;
    for (int k = t; k < L; k += 256) {
        const uint4* Kr = reinterpret_cast<const uint4*>(Kbase + (size_t)k * DK);
        float acc = 0.f;
        #pragma unroll
        for (int d8 = 0; d8 < 8; ++d8) {   // 8 uint4 loads = 64 bf16
            uint4 kv = Kr[d8];
            float2 f0 = bf2u_to_f2(kv.x), f1 = bf2u_to_f2(kv.y);
            float2 f2 = bf2u_to_f2(kv.z), f3 = bf2u_to_f2(kv.w);
            const int d = d8 * 8;
            acc = fmaf(qs[d + 0], f0.x, acc); acc = fmaf(qs[d + 1], f0.y, acc);
            acc = fmaf(qs[d + 2], f1.x, acc); acc = fmaf(qs[d + 3], f1.y, acc);
            acc = fmaf(qs[d + 4], f2.x, acc); acc = fmaf(qs[d + 5], f2.y, acc);
            acc = fmaf(qs[d + 6], f3.x, acc); acc = fmaf(qs[d + 7], f3.y, acc);
        }
        acc *= 0.125f;   // dk^-0.5
        sc[k] = acc;
        lmax = fmaxf(lmax, acc);
    }
    rbuf[t] = lmax;
    __syncthreads();
    for (int s2 = 128; s2 > 0; s2 >>= 1) {
        if (t < s2) rbuf[t] = fmaxf(rbuf[t], rbuf[t + s2]);
        __syncthreads();
    }
    const float m = rbuf[0];
    __syncthreads();

    float lsum = 0.f;
    for (int k = t; k < L; k += 256) {
        float e = __expf(sc[k] - m);
        sc[k] = e;
        lsum += e;
    }
    rbuf[t] = lsum;
    __syncthreads();
    for (int s2 = 128; s2 > 0; s2 >>= 1) {
        if (t < s2) rbuf[t] += rbuf[t + s2];
        __syncthreads();
    }
    const float inv = 1.f / rbuf[0];
    __syncthreads();

    const int kg = t >> 6, d = t & 63;
    float o = 0.f;
    const bf16* Vb = V + (size_t)bh * SEQ * DK + d;
    for (int k = kg; k < L; k += 4) {
        o = fmaf(sc[k], __bfloat162float(Vb[(size_t)k * DK]), o);
    }
    obuf[kg][d] = o;
    __syncthreads();
    if (t < DK) {
        const float r = (obuf[0][t] + obuf[1][t]) + (obuf[2][t] + obuf[3][t]);
        const int b = bh >> 4, h = bh & 15;
        O[((size_t)b * SEQ + q) * D_MODEL + h * DK + t] = r * inv;
    }
}

// ---------------------------------------------------------------------------
// Kernel 3: output projection (FP32 in / FP32 out), in-place on d_out.
// Each block stages its own row to LDS before writing only that row.
// ---------------------------------------------------------------------------
__global__ __launch_bounds__(256) void oproj_kernel(
    const float* __restrict__ Oin, const float* __restrict__ Wo,
    float* __restrict__ out)
{
    __shared__ float xs[D_MODEL];
    const int bs = blockIdx.x;
    const int t = threadIdx.x;
    const float* orow = Oin + (size_t)bs * D_MODEL;
    for (int i = t; i < D_MODEL; i += 256) xs[i] = orow[i];
    __syncthreads();

    #pragma unroll
    for (int j = 0; j < 4; ++j) {
        const int n = t + 256 * j;
        const float4* w4 = reinterpret_cast<const float4*>(Wo + (size_t)n * D_MODEL);
        float acc = 0.f;
        #pragma unroll 8
        for (int k = 0; k < D_MODEL / 4; ++k) {
            float4 wf = w4[k];
            acc = fmaf(xs[4 * k],     wf.x, acc);
            acc = fmaf(xs[4 * k + 1], wf.y, acc);
            acc = fmaf(xs[4 * k + 2], wf.z, acc);
            acc = fmaf(xs[4 * k + 3], wf.w, acc);
        }
        out[(size_t)bs * D_MODEL + n] = acc;
    }
}

extern "C" void kernel_launch(void* const* d_in, const int* in_sizes, int n_in,
                              void* d_out, int out_size, void* d_ws, size_t ws_size,
                              hipStream_t stream)
{
    const float* x   = (const float*)d_in[0];
    const int*   pos = (const int*)d_in[1];
    const float* Wq  = (const float*)d_in[2];
    const float* Wk  = (const float*)d_in[3];
    const float* Wv  = (const float*)d_in[4];
    const float* Wo  = (const float*)d_in[5];
    float* out = (float*)d_out;

    const size_t qkv_elems = (size_t)BATCH * NUM_HEADS * SEQ * DK;  // 4M
    bf16* Q = (bf16*)d_ws;
    bf16* K = Q + qkv_elems;
    bf16* V = K + qkv_elems;   // total 24 MB bf16

    qkv_rope_kernel<<<BATCH * SEQ, 256, 0, stream>>>(x, pos, Wq, Wk, Wv, Q, K, V);
    attn_kernel<<<dim3(SEQ, BATCH * NUM_HEADS), 256, 0, stream>>>(Q, K, V, out);
    oproj_kernel<<<BATCH * SEQ, 256, 0, stream>>>(out, Wo, out);
}

// Round 5
// 2662.097 us; speedup vs baseline: 3.6113x; 3.6113x over previous
//
#include <hip/hip_runtime.h>
#include <hip/hip_bf16.h>
#include <math.h>

typedef __hip_bfloat16 bf16;
typedef __attribute__((ext_vector_type(8))) short short8;
typedef __attribute__((ext_vector_type(4))) float floatx4;

#define D_MODEL 1024
#define NUM_HEADS 16
#define DK 64
#define SEQ 2048
#define BATCH 2
#define MROWS (BATCH * SEQ)          // 4096
#define KDIM 1024
#define SEG_X ((size_t)MROWS * D_MODEL)      // 4194304
#define SEG_W ((size_t)D_MODEL * D_MODEL)    // 1048576

__device__ inline float2 bf2u_to_f2(unsigned u) {
    __hip_bfloat162 h = *reinterpret_cast<__hip_bfloat162*>(&u);
    return __bfloat1622float2(h);
}

__device__ inline void gload16(const void* g, void* l) {
    __builtin_amdgcn_global_load_lds(
        (const __attribute__((address_space(1))) void*)g,
        (__attribute__((address_space(3))) void*)l, 16, 0, 0);
}

__device__ inline void store_c(bf16* p, float v)  { *p = __float2bfloat16(v); }
__device__ inline void store_c(float* p, float v) { *p = v; }

// ---------------------------------------------------------------------------
// Cast fp32 inputs to bf16 workspace buffers (x -> xb, Wq|Wk|Wv -> w_all,
// Wo -> wob). 8M elements, 4 per thread, float4 loads.
// ---------------------------------------------------------------------------
__global__ __launch_bounds__(256) void cast_kernel(
    const float* __restrict__ x,  const float* __restrict__ Wq,
    const float* __restrict__ Wk, const float* __restrict__ Wv,
    const float* __restrict__ Wo,
    bf16* __restrict__ xb, bf16* __restrict__ w_all, bf16* __restrict__ wob)
{
    const size_t i = ((size_t)blockIdx.x * 256 + threadIdx.x) * 4;
    const float* src; bf16* dst;
    if (i < SEG_X)                    { src = x  + i;                       dst = xb + i; }
    else if (i < SEG_X + SEG_W)       { src = Wq + (i - SEG_X);             dst = w_all + (i - SEG_X); }
    else if (i < SEG_X + 2 * SEG_W)   { src = Wk + (i - SEG_X - SEG_W);     dst = w_all + (i - SEG_X); }
    else if (i < SEG_X + 3 * SEG_W)   { src = Wv + (i - SEG_X - 2 * SEG_W); dst = w_all + (i - SEG_X); }
    else                              { src = Wo + (i - SEG_X - 3 * SEG_W); dst = wob + (i - SEG_X - 3 * SEG_W); }
    float4 v = *reinterpret_cast<const float4*>(src);
    __hip_bfloat162 lo, hi;
    lo.x = __float2bfloat16(v.x); lo.y = __float2bfloat16(v.y);
    hi.x = __float2bfloat16(v.z); hi.y = __float2bfloat16(v.w);
    __hip_bfloat162* d2 = reinterpret_cast<__hip_bfloat162*>(dst);
    d2[0] = lo; d2[1] = hi;
}

// ---------------------------------------------------------------------------
// bf16 GEMM, C[m][n] = sum_k A[m][k] * B[n][k]  (B^T layout, m93/m97 style).
// 128x128 tile, BK=32, 4 waves x (64x64), global_load_lds width-16 staging,
// mfma_f32_16x16x32_bf16. B is given as up to 3 row-segments of 1024 rows
// (for the fused QKV weight); a 128-row N-tile never straddles segments.
// ---------------------------------------------------------------------------
template <typename OutT>
__global__ __launch_bounds__(256) void gemm_bt_kernel(
    const bf16* __restrict__ A,
    const bf16* __restrict__ B0, const bf16* __restrict__ B1,
    const bf16* __restrict__ B2,
    OutT* __restrict__ C, int N)
{
    __shared__ bf16 ldsA[128 * 32];
    __shared__ bf16 ldsB[128 * 32];

    const int tileM = blockIdx.x * 128;
    const int tileN = blockIdx.y * 128;
    const int t = threadIdx.x;
    const int w = t >> 6, j = t & 63;
    const int wm = (w & 1) * 64, wn = (w >> 1) * 64;
    const int l15 = j & 15, lq = j >> 4;

    const bf16* Bp; int nloc;
    if (tileN < 1024)      { Bp = B0; nloc = tileN; }
    else if (tileN < 2048) { Bp = B1; nloc = tileN - 1024; }
    else                   { Bp = B2; nloc = tileN - 2048; }

    floatx4 acc[4][4];
    #pragma unroll
    for (int a = 0; a < 4; ++a)
        #pragma unroll
        for (int b = 0; b < 4; ++b)
            acc[a][b] = (floatx4){0.f, 0.f, 0.f, 0.f};

    const int arow = j >> 2;        // 0..15: row within 16-row stage group
    const int acol = (j & 3) * 8;   // 0/8/16/24: bf16 element offset (16B)

    for (int kk = 0; kk < KDIM; kk += 32) {
        #pragma unroll
        for (int i = 0; i < 2; ++i) {
            const int rb = 32 * w + 16 * i;   // stage-group base row
            gload16(A  + (size_t)(tileM + rb + arow) * KDIM + kk + acol,
                    &ldsA[rb * 32]);
            gload16(Bp + (size_t)(nloc  + rb + arow) * KDIM + kk + acol,
                    &ldsB[rb * 32]);
        }
        __syncthreads();

        short8 af[4], bfr[4];
        #pragma unroll
        for (int mt = 0; mt < 4; ++mt)
            af[mt] = *reinterpret_cast<const short8*>(
                &ldsA[(wm + mt * 16 + l15) * 32 + lq * 8]);
        #pragma unroll
        for (int nt = 0; nt < 4; ++nt)
            bfr[nt] = *reinterpret_cast<const short8*>(
                &ldsB[(wn + nt * 16 + l15) * 32 + lq * 8]);
        #pragma unroll
        for (int mt = 0; mt < 4; ++mt)
            #pragma unroll
            for (int nt = 0; nt < 4; ++nt)
                acc[mt][nt] = __builtin_amdgcn_mfma_f32_16x16x32_bf16(
                    af[mt], bfr[nt], acc[mt][nt], 0, 0, 0);
        __syncthreads();
    }

    // Epilogue. C/D layout: col = lane&15, row = (lane>>4)*4 + reg.
    #pragma unroll
    for (int mt = 0; mt < 4; ++mt) {
        #pragma unroll
        for (int nt = 0; nt < 4; ++nt) {
            const int col = tileN + wn + nt * 16 + l15;
            #pragma unroll
            for (int r = 0; r < 4; ++r) {
                const int row = tileM + wm + mt * 16 + lq * 4 + r;
                store_c(C + (size_t)row * N + col, acc[mt][nt][r]);
            }
        }
    }
}

// ---------------------------------------------------------------------------
// In-place RoPE on the fused QKV buffer (rows of 3072: Q|K|V, 1024 each).
// One block per (b,s) row; rotates Q and K pairs; V untouched.
// ---------------------------------------------------------------------------
__global__ __launch_bounds__(256) void rope_kernel(
    bf16* __restrict__ qkv, const int* __restrict__ pos)
{
    const int bs = blockIdx.x;
    const int s = bs & (SEQ - 1);
    const int t = threadIdx.x;
    const int p = (pos[1] == 0) ? pos[2 * s] : pos[s];
    bf16* row = qkv + (size_t)bs * 3072;

    #pragma unroll
    for (int part = 0; part < 2; ++part) {       // Q then K
        bf16* base = row + part * 1024;
        #pragma unroll
        for (int jj = 0; jj < 2; ++jj) {
            const int pr = t + 256 * jj;          // pair index 0..511
            const int i = pr & 31;                // pair within head
            const float freq = __expf((float)(2 * i) * (-9.2103403719761836f / 64.f));
            const float ang = (float)p * freq;
            const float sn = sinf(ang), cs = cosf(ang);
            __hip_bfloat162* pp = reinterpret_cast<__hip_bfloat162*>(base + 2 * pr);
            float2 v = __bfloat1622float2(*pp);
            __hip_bfloat162 o;
            o.x = __float2bfloat16(v.x * cs - v.y * sn);
            o.y = __float2bfloat16(v.x * sn + v.y * cs);
            *pp = o;
        }
    }
}

// ---------------------------------------------------------------------------
// Causal attention, one block per (b,h,q) row, reading the fused QKV buffer
// (row stride 3072, Q at +0, K at +1024, V at +2048). Writes bf16 O rows.
// ---------------------------------------------------------------------------
__global__ __launch_bounds__(256) void attn_kernel(
    const bf16* __restrict__ qkv, bf16* __restrict__ O)
{
    const int q = blockIdx.x;
    const int bh = blockIdx.y;
    const int b = bh >> 4, h = bh & 15;
    const int t = threadIdx.x;
    __shared__ float sc[SEQ];
    __shared__ float qs[DK];
    __shared__ float rbuf[256];
    __shared__ float obuf[4][DK];

    const bf16* rowbase = qkv + (size_t)b * SEQ * 3072;
    const bf16* Qr = rowbase + (size_t)q * 3072 + h * 64;
    if (t < DK) qs[t] = __bfloat162float(Qr[t]);
    __syncthreads();

    const int L = q + 1;
    const bf16* Kbase = rowbase + 1024 + h * 64;

    float lmax = -3.0e38f;
    for (int k = t; k < L; k += 256) {
        const uint4* Kr = reinterpret_cast<const uint4*>(Kbase + (size_t)k * 3072);
        float acc = 0.f;
        #pragma unroll
        for (int d8 = 0; d8 < 8; ++d8) {
            uint4 kv = Kr[d8];
            float2 f0 = bf2u_to_f2(kv.x), f1 = bf2u_to_f2(kv.y);
            float2 f2 = bf2u_to_f2(kv.z), f3 = bf2u_to_f2(kv.w);
            const int d = d8 * 8;
            acc = fmaf(qs[d + 0], f0.x, acc); acc = fmaf(qs[d + 1], f0.y, acc);
            acc = fmaf(qs[d + 2], f1.x, acc); acc = fmaf(qs[d + 3], f1.y, acc);
            acc = fmaf(qs[d + 4], f2.x, acc); acc = fmaf(qs[d + 5], f2.y, acc);
            acc = fmaf(qs[d + 6], f3.x, acc); acc = fmaf(qs[d + 7], f3.y, acc);
        }
        acc *= 0.125f;
        sc[k] = acc;
        lmax = fmaxf(lmax, acc);
    }
    rbuf[t] = lmax;
    __syncthreads();
    for (int s2 = 128; s2 > 0; s2 >>= 1) {
        if (t < s2) rbuf[t] = fmaxf(rbuf[t], rbuf[t + s2]);
        __syncthreads();
    }
    const float m = rbuf[0];
    __syncthreads();

    float lsum = 0.f;
    for (int k = t; k < L; k += 256) {
        float e = __expf(sc[k] - m);
        sc[k] = e;
        lsum += e;
    }
    rbuf[t] = lsum;
    __syncthreads();
    for (int s2 = 128; s2 > 0; s2 >>= 1) {
        if (t < s2) rbuf[t] += rbuf[t + s2];
        __syncthreads();
    }
    const float inv = 1.f / rbuf[0];
    __syncthreads();

    const int kg = t >> 6, d = t & 63;
    float o = 0.f;
    const bf16* Vb = rowbase + 2048 + h * 64 + d;
    for (int k = kg; k < L; k += 4) {
        o = fmaf(sc[k], __bfloat162float(Vb[(size_t)k * 3072]), o);
    }
    obuf[kg][d] = o;
    __syncthreads();
    if (t < DK) {
        const float r = (obuf[0][t] + obuf[1][t]) + (obuf[2][t] + obuf[3][t]);
        O[((size_t)b * SEQ + q) * D_MODEL + h * DK + t] =
            __float2bfloat16(r * inv);
    }
}

extern "C" void kernel_launch(void* const* d_in, const int* in_sizes, int n_in,
                              void* d_out, int out_size, void* d_ws, size_t ws_size,
                              hipStream_t stream)
{
    const float* x   = (const float*)d_in[0];
    const int*   pos = (const int*)d_in[1];
    const float* Wq  = (const float*)d_in[2];
    const float* Wk  = (const float*)d_in[3];
    const float* Wv  = (const float*)d_in[4];
    const float* Wo  = (const float*)d_in[5];
    float* out = (float*)d_out;

    // ws layout (bf16 elements): xb [4M] | w_all [3M] | wob [1M] | qkv [12.6M]
    bf16* xb    = (bf16*)d_ws;              // 8 MB; reused as ob after GEMM1
    bf16* w_all = xb + SEG_X;               // 6 MB (Wq|Wk|Wv rows)
    bf16* wob   = w_all + 3 * SEG_W;        // 2 MB
    bf16* qkvb  = wob + SEG_W;              // 24 MB (4096 x 3072)
    bf16* ob    = xb;                       // reuse: x dead after GEMM1

    cast_kernel<<<8192, 256, 0, stream>>>(x, Wq, Wk, Wv, Wo, xb, w_all, wob);
    gemm_bt_kernel<bf16><<<dim3(32, 24), 256, 0, stream>>>(
        xb, w_all, w_all + SEG_W, w_all + 2 * SEG_W, qkvb, 3072);
    rope_kernel<<<MROWS, 256, 0, stream>>>(qkvb, pos);
    attn_kernel<<<dim3(SEQ, BATCH * NUM_HEADS), 256, 0, stream>>>(qkvb, ob);
    gemm_bt_kernel<float><<<dim3(32, 8), 256, 0, stream>>>(
        ob, wob, wob, wob, out, 1024);
}

// Round 6
// 290.754 us; speedup vs baseline: 33.0641x; 9.1558x over previous
//
#include <hip/hip_runtime.h>
#include <hip/hip_bf16.h>
#include <math.h>

typedef __hip_bfloat16 bf16;
typedef __attribute__((ext_vector_type(8))) short short8;
typedef __attribute__((ext_vector_type(4))) short short4v;
typedef __attribute__((ext_vector_type(4))) float floatx4;

#define D_MODEL 1024
#define NUM_HEADS 16
#define DK 64
#define SEQ 2048
#define BATCH 2
#define MROWS (BATCH * SEQ)          // 4096
#define KDIM 1024
#define SEG_X ((size_t)MROWS * D_MODEL)      // 4194304
#define SEG_W ((size_t)D_MODEL * D_MODEL)    // 1048576

__device__ inline void gload16(const void* g, void* l) {
    __builtin_amdgcn_global_load_lds(
        (const __attribute__((address_space(1))) void*)g,
        (__attribute__((address_space(3))) void*)l, 16, 0, 0);
}

__device__ inline void store_c(bf16* p, float v)  { *p = __float2bfloat16(v); }
__device__ inline void store_c(float* p, float v) { *p = v; }

// ---------------------------------------------------------------------------
// Cast fp32 inputs to bf16 workspace buffers.
// ---------------------------------------------------------------------------
__global__ __launch_bounds__(256) void cast_kernel(
    const float* __restrict__ x,  const float* __restrict__ Wq,
    const float* __restrict__ Wk, const float* __restrict__ Wv,
    const float* __restrict__ Wo,
    bf16* __restrict__ xb, bf16* __restrict__ w_all, bf16* __restrict__ wob)
{
    const size_t i = ((size_t)blockIdx.x * 256 + threadIdx.x) * 4;
    const float* src; bf16* dst;
    if (i < SEG_X)                    { src = x  + i;                       dst = xb + i; }
    else if (i < SEG_X + SEG_W)       { src = Wq + (i - SEG_X);             dst = w_all + (i - SEG_X); }
    else if (i < SEG_X + 2 * SEG_W)   { src = Wk + (i - SEG_X - SEG_W);     dst = w_all + (i - SEG_X); }
    else if (i < SEG_X + 3 * SEG_W)   { src = Wv + (i - SEG_X - 2 * SEG_W); dst = w_all + (i - SEG_X); }
    else                              { src = Wo + (i - SEG_X - 3 * SEG_W); dst = wob + (i - SEG_X - 3 * SEG_W); }
    float4 v = *reinterpret_cast<const float4*>(src);
    __hip_bfloat162 lo, hi;
    lo.x = __float2bfloat16(v.x); lo.y = __float2bfloat16(v.y);
    hi.x = __float2bfloat16(v.z); hi.y = __float2bfloat16(v.w);
    __hip_bfloat162* d2 = reinterpret_cast<__hip_bfloat162*>(dst);
    d2[0] = lo; d2[1] = hi;
}

// ---------------------------------------------------------------------------
// bf16 GEMM, C[m][n] = sum_k A[m][k]*B[n][k] (m97 structure). Unchanged.
// ---------------------------------------------------------------------------
template <typename OutT>
__global__ __launch_bounds__(256) void gemm_bt_kernel(
    const bf16* __restrict__ A,
    const bf16* __restrict__ B0, const bf16* __restrict__ B1,
    const bf16* __restrict__ B2,
    OutT* __restrict__ C, int N)
{
    __shared__ bf16 ldsA[128 * 32];
    __shared__ bf16 ldsB[128 * 32];

    const int tileM = blockIdx.x * 128;
    const int tileN = blockIdx.y * 128;
    const int t = threadIdx.x;
    const int w = t >> 6, j = t & 63;
    const int wm = (w & 1) * 64, wn = (w >> 1) * 64;
    const int l15 = j & 15, lq = j >> 4;

    const bf16* Bp; int nloc;
    if (tileN < 1024)      { Bp = B0; nloc = tileN; }
    else if (tileN < 2048) { Bp = B1; nloc = tileN - 1024; }
    else                   { Bp = B2; nloc = tileN - 2048; }

    floatx4 acc[4][4];
    #pragma unroll
    for (int a = 0; a < 4; ++a)
        #pragma unroll
        for (int b = 0; b < 4; ++b)
            acc[a][b] = (floatx4){0.f, 0.f, 0.f, 0.f};

    const int arow = j >> 2;
    const int acol = (j & 3) * 8;

    for (int kk = 0; kk < KDIM; kk += 32) {
        #pragma unroll
        for (int i = 0; i < 2; ++i) {
            const int rb = 32 * w + 16 * i;
            gload16(A  + (size_t)(tileM + rb + arow) * KDIM + kk + acol,
                    &ldsA[rb * 32]);
            gload16(Bp + (size_t)(nloc  + rb + arow) * KDIM + kk + acol,
                    &ldsB[rb * 32]);
        }
        __syncthreads();

        short8 af[4], bfr[4];
        #pragma unroll
        for (int mt = 0; mt < 4; ++mt)
            af[mt] = *reinterpret_cast<const short8*>(
                &ldsA[(wm + mt * 16 + l15) * 32 + lq * 8]);
        #pragma unroll
        for (int nt = 0; nt < 4; ++nt)
            bfr[nt] = *reinterpret_cast<const short8*>(
                &ldsB[(wn + nt * 16 + l15) * 32 + lq * 8]);
        #pragma unroll
        for (int mt = 0; mt < 4; ++mt)
            #pragma unroll
            for (int nt = 0; nt < 4; ++nt)
                acc[mt][nt] = __builtin_amdgcn_mfma_f32_16x16x32_bf16(
                    af[mt], bfr[nt], acc[mt][nt], 0, 0, 0);
        __syncthreads();
    }

    #pragma unroll
    for (int mt = 0; mt < 4; ++mt) {
        #pragma unroll
        for (int nt = 0; nt < 4; ++nt) {
            const int col = tileN + wn + nt * 16 + l15;
            #pragma unroll
            for (int r = 0; r < 4; ++r) {
                const int row = tileM + wm + mt * 16 + lq * 4 + r;
                store_c(C + (size_t)row * N + col, acc[mt][nt][r]);
            }
        }
    }
}

// ---------------------------------------------------------------------------
// In-place RoPE on the fused QKV buffer. Unchanged.
// ---------------------------------------------------------------------------
__global__ __launch_bounds__(256) void rope_kernel(
    bf16* __restrict__ qkv, const int* __restrict__ pos)
{
    const int bs = blockIdx.x;
    const int s = bs & (SEQ - 1);
    const int t = threadIdx.x;
    const int p = (pos[1] == 0) ? pos[2 * s] : pos[s];
    bf16* row = qkv + (size_t)bs * 3072;

    #pragma unroll
    for (int part = 0; part < 2; ++part) {
        bf16* base = row + part * 1024;
        #pragma unroll
        for (int jj = 0; jj < 2; ++jj) {
            const int pr = t + 256 * jj;
            const int i = pr & 31;
            const float freq = __expf((float)(2 * i) * (-9.2103403719761836f / 64.f));
            const float ang = (float)p * freq;
            const float sn = sinf(ang), cs = cosf(ang);
            __hip_bfloat162* pp = reinterpret_cast<__hip_bfloat162*>(base + 2 * pr);
            float2 v = __bfloat1622float2(*pp);
            __hip_bfloat162 o;
            o.x = __float2bfloat16(v.x * cs - v.y * sn);
            o.y = __float2bfloat16(v.x * sn + v.y * cs);
            *pp = o;
        }
    }
}

// ---------------------------------------------------------------------------
// MFMA flash attention. Block = 4 waves = one (b,h) x 64-row Q tile.
// Wave w owns Q rows [qt*64+16w, +16). K/V tiles of 64, causal iteration.
// Layouts: A/B-frag row=lane&15, k=(lane>>4)*8+j; C/D col=lane&15,
// row=(lane>>4)*4+reg (verified by the working GEMM above).
// ---------------------------------------------------------------------------
__global__ __launch_bounds__(256) void flash_attn_kernel(
    const bf16* __restrict__ qkv, bf16* __restrict__ O)
{
    __shared__ bf16 Qs[2][64][32];     // [panel p: k in dk][row][32]
    __shared__ bf16 Ks[2][64][32];
    __shared__ bf16 Vt[2][64][36];     // V^T: [panel kp][d][k%32], pad->36
    __shared__ bf16 Ps[4][2][16][32];  // per-wave P: [wave][kp][row][k%32]

    const int qt = gridDim.x - 1 - blockIdx.x;   // heavy tiles first
    const int bh = blockIdx.y;
    const int b = bh >> 4, h = bh & 15;
    const int t = threadIdx.x;
    const int w = t >> 6, lane = t & 63;
    const int l15 = lane & 15, lq = lane >> 4;

    const bf16* base = qkv + (size_t)b * SEQ * 3072 + h * 64;

    // stage Q tile (once): wave w stages its 16 rows into both panels
    const int srow = 16 * w + (lane >> 2);
    const int scol = (lane & 3) * 8;
    #pragma unroll
    for (int p = 0; p < 2; ++p)
        gload16(base + (size_t)(qt * 64 + srow) * 3072 + p * 32 + scol,
                &Qs[p][16 * w][0]);

    floatx4 accO[4];
    #pragma unroll
    for (int nt = 0; nt < 4; ++nt) accO[nt] = (floatx4){0.f, 0.f, 0.f, 0.f};
    float m_i[4], l_i[4];
    #pragma unroll
    for (int r = 0; r < 4; ++r) { m_i[r] = -1e30f; l_i[r] = 0.f; }

    for (int kt = 0; kt <= qt; ++kt) {
        // ---- stage K tile (global_load_lds) ----
        #pragma unroll
        for (int p = 0; p < 2; ++p)
            gload16(base + 1024 + (size_t)(kt * 64 + srow) * 3072 + p * 32 + scol,
                    &Ks[p][16 * w][0]);
        // ---- stage V tile transposed ----
        #pragma unroll
        for (int s2 = 0; s2 < 2; ++s2) {
            const int kk = 16 * w + 8 * s2 + (lane >> 3);   // local k row
            const int d0 = (lane & 7) * 8;
            const uint4 v = *reinterpret_cast<const uint4*>(
                base + 2048 + (size_t)(kt * 64 + kk) * 3072 + d0);
            const int kp = kk >> 5, k32 = kk & 31;
            unsigned uu[4] = {v.x, v.y, v.z, v.w};
            #pragma unroll
            for (int i = 0; i < 4; ++i) {
                __hip_bfloat162 pr = *reinterpret_cast<__hip_bfloat162*>(&uu[i]);
                Vt[kp][d0 + 2 * i][k32]     = pr.x;
                Vt[kp][d0 + 2 * i + 1][k32] = pr.y;
            }
        }
        __syncthreads();

        // ---- QK^T ----
        floatx4 accS[4];
        #pragma unroll
        for (int nt = 0; nt < 4; ++nt) accS[nt] = (floatx4){0.f, 0.f, 0.f, 0.f};
        #pragma unroll
        for (int p = 0; p < 2; ++p) {
            const short8 aq = *reinterpret_cast<const short8*>(
                &Qs[p][16 * w + l15][lq * 8]);
            #pragma unroll
            for (int nt = 0; nt < 4; ++nt) {
                const short8 bk = *reinterpret_cast<const short8*>(
                    &Ks[p][nt * 16 + l15][lq * 8]);
                accS[nt] = __builtin_amdgcn_mfma_f32_16x16x32_bf16(
                    aq, bk, accS[nt], 0, 0, 0);
            }
        }

        // ---- scale + causal mask ----
        float sv[4][4];
        const int rowloc = 16 * w + lq * 4;   // + r
        const bool diag = (kt == qt);
        #pragma unroll
        for (int nt = 0; nt < 4; ++nt) {
            const int colloc = nt * 16 + l15;
            #pragma unroll
            for (int r = 0; r < 4; ++r) {
                float s = accS[nt][r] * 0.125f;
                if (diag && colloc > rowloc + r) s = -1e30f;
                sv[nt][r] = s;
            }
        }

        // ---- online softmax ----
        float rm[4], rs[4], alpha[4];
        #pragma unroll
        for (int r = 0; r < 4; ++r) {
            float v0 = fmaxf(fmaxf(sv[0][r], sv[1][r]), fmaxf(sv[2][r], sv[3][r]));
            v0 = fmaxf(v0, __shfl_xor(v0, 1));
            v0 = fmaxf(v0, __shfl_xor(v0, 2));
            v0 = fmaxf(v0, __shfl_xor(v0, 4));
            v0 = fmaxf(v0, __shfl_xor(v0, 8));
            const float mn = fmaxf(m_i[r], v0);
            alpha[r] = __expf(m_i[r] - mn);
            m_i[r] = mn;
            rm[r] = mn;
        }
        // exp, bf16-round, write P, accumulate row sums of rounded P
        #pragma unroll
        for (int r = 0; r < 4; ++r) rs[r] = 0.f;
        #pragma unroll
        for (int nt = 0; nt < 4; ++nt) {
            #pragma unroll
            for (int r = 0; r < 4; ++r) {
                const float e = __expf(sv[nt][r] - rm[r]);
                const bf16 eb = __float2bfloat16(e);
                Ps[w][nt >> 1][lq * 4 + r][(nt & 1) * 16 + l15] = eb;
                rs[r] += __bfloat162float(eb);
            }
        }
        #pragma unroll
        for (int r = 0; r < 4; ++r) {
            float s0 = rs[r];
            s0 += __shfl_xor(s0, 1);
            s0 += __shfl_xor(s0, 2);
            s0 += __shfl_xor(s0, 4);
            s0 += __shfl_xor(s0, 8);
            l_i[r] = l_i[r] * alpha[r] + s0;
        }
        // rescale O accumulators
        #pragma unroll
        for (int nt = 0; nt < 4; ++nt)
            #pragma unroll
            for (int r = 0; r < 4; ++r)
                accO[nt][r] *= alpha[r];

        // ---- PV (P from own-wave LDS region; V^T from shared Vt) ----
        #pragma unroll
        for (int kp = 0; kp < 2; ++kp) {
            const short8 ap = *reinterpret_cast<const short8*>(
                &Ps[w][kp][l15][lq * 8]);
            #pragma unroll
            for (int nt = 0; nt < 4; ++nt) {
                const short4v lo = *reinterpret_cast<const short4v*>(
                    &Vt[kp][nt * 16 + l15][lq * 8]);
                const short4v hi = *reinterpret_cast<const short4v*>(
                    &Vt[kp][nt * 16 + l15][lq * 8 + 4]);
                short8 bv;
                #pragma unroll
                for (int i = 0; i < 4; ++i) { bv[i] = lo[i]; bv[4 + i] = hi[i]; }
                accO[nt] = __builtin_amdgcn_mfma_f32_16x16x32_bf16(
                    ap, bv, accO[nt], 0, 0, 0);
            }
        }
        __syncthreads();
    }

    // ---- epilogue: O /= l, write bf16 ----
    #pragma unroll
    for (int r = 0; r < 4; ++r) {
        const float inv = 1.f / l_i[r];
        const int qrow = qt * 64 + 16 * w + lq * 4 + r;
        #pragma unroll
        for (int nt = 0; nt < 4; ++nt) {
            O[((size_t)(b * SEQ + qrow)) * D_MODEL + h * DK + nt * 16 + l15] =
                __float2bfloat16(accO[nt][r] * inv);
        }
    }
}

extern "C" void kernel_launch(void* const* d_in, const int* in_sizes, int n_in,
                              void* d_out, int out_size, void* d_ws, size_t ws_size,
                              hipStream_t stream)
{
    const float* x   = (const float*)d_in[0];
    const int*   pos = (const int*)d_in[1];
    const float* Wq  = (const float*)d_in[2];
    const float* Wk  = (const float*)d_in[3];
    const float* Wv  = (const float*)d_in[4];
    const float* Wo  = (const float*)d_in[5];
    float* out = (float*)d_out;

    // ws layout (bf16): xb [4M] | w_all [3M] | wob [1M] | qkv [12.6M]
    bf16* xb    = (bf16*)d_ws;
    bf16* w_all = xb + SEG_X;
    bf16* wob   = w_all + 3 * SEG_W;
    bf16* qkvb  = wob + SEG_W;
    bf16* ob    = xb;                       // reuse: x dead after GEMM1

    cast_kernel<<<8192, 256, 0, stream>>>(x, Wq, Wk, Wv, Wo, xb, w_all, wob);
    gemm_bt_kernel<bf16><<<dim3(32, 24), 256, 0, stream>>>(
        xb, w_all, w_all + SEG_W, w_all + 2 * SEG_W, qkvb, 3072);
    rope_kernel<<<MROWS, 256, 0, stream>>>(qkvb, pos);
    flash_attn_kernel<<<dim3(32, 32), 256, 0, stream>>>(qkvb, ob);
    gemm_bt_kernel<float><<<dim3(32, 8), 256, 0, stream>>>(
        ob, wob, wob, wob, out, 1024);
}